// Round 3
// baseline (11959.612 us; speedup 1.0000x reference)
//
#include <hip/hip_runtime.h>
#include <hip/hip_bf16.h>

// =============================================================
// Embedding: out[b,s,d] = emb[tok[b,s], d]*sqrt(512) + pe[s,d]
// =============================================================
__global__ void embed_kernel(const int* __restrict__ tok, const float* __restrict__ emb,
                             const float* __restrict__ pe, float* __restrict__ out,
                             int S, int total) {
    int i = blockIdx.x * 256 + threadIdx.x;
    if (i >= total) return;
    int d  = i & 511;
    int bs = i >> 9;
    int s  = bs % S;
    int t  = tok[bs];
    out[i] = emb[(size_t)t * 512 + d] * 22.62741699796952f + pe[(size_t)s * 512 + d];
}

// =============================================================
// LayerNorm (torch variant: unbiased std, divide by (std+eps))
// one block (256 thr) per row of 512
// =============================================================
__global__ __launch_bounds__(256)
void layernorm_kernel(const float* __restrict__ x, const float* __restrict__ g,
                      const float* __restrict__ bta, float* __restrict__ out) {
    __shared__ float red[256];
    const int row = blockIdx.x, tid = threadIdx.x;
    const float* xr = x + (size_t)row * 512;
    float v0 = xr[tid], v1 = xr[tid + 256];
    red[tid] = v0 + v1;
    __syncthreads();
    for (int st = 128; st > 0; st >>= 1) { if (tid < st) red[tid] += red[tid + st]; __syncthreads(); }
    float mean = red[0] * (1.f / 512.f);
    __syncthreads();
    float d0 = v0 - mean, d1 = v1 - mean;
    red[tid] = d0 * d0 + d1 * d1;
    __syncthreads();
    for (int st = 128; st > 0; st >>= 1) { if (tid < st) red[tid] += red[tid + st]; __syncthreads(); }
    float var = red[0] * (1.f / 511.f);            // unbiased (d-1)
    float inv = 1.f / (sqrtf(var) + 1e-6f);        // (std + eps)
    out[(size_t)row * 512 + tid]       = g[tid] * d0 * inv + bta[tid];
    out[(size_t)row * 512 + tid + 256] = g[tid + 256] * d1 * inv + bta[tid + 256];
}

// =============================================================
// Generic GEMM: C[M,N] = act(A[M,K] @ W[K,N] + bias (+res)), all f32
// 64x64 tile, 256 threads, 4x4 per thread, KT=32.
// =============================================================
template<int RELU, int RES>
__global__ __launch_bounds__(256)
void gemm_kernel(const float* __restrict__ A, int lda,
                 const float* __restrict__ W, int ldw,
                 const float* __restrict__ bias,
                 const float* __restrict__ res, int ldres,
                 float* __restrict__ C, int ldc,
                 int M, int N, int K) {
    __shared__ float As[32][68];
    __shared__ float Ws[32][68];
    const int tid = threadIdx.x;
    const int tx = tid & 15, ty = tid >> 4;
    const int m0 = blockIdx.y * 64, n0 = blockIdx.x * 64;

    float acc[4][4];
#pragma unroll
    for (int i = 0; i < 4; ++i)
#pragma unroll
        for (int j = 0; j < 4; ++j) acc[i][j] = 0.f;

    const int kqa = (tid & 7) * 4;   // A k-offset within tile
    const int ma  = tid >> 3;        // 0..31
    const int nw  = (tid & 15) * 4;  // W n-offset within tile
    const int kw  = tid >> 4;        // 0..15
    const bool fullW = ((ldw & 3) == 0) && (n0 + 64 <= N);  // block-uniform

    for (int kb = 0; kb < K; kb += 32) {
#pragma unroll
        for (int it = 0; it < 2; ++it) {
            int mm = ma + it * 32;
            const float4 av = *(const float4*)(A + (size_t)(m0 + mm) * lda + kb + kqa);
            As[kqa + 0][mm] = av.x;
            As[kqa + 1][mm] = av.y;
            As[kqa + 2][mm] = av.z;
            As[kqa + 3][mm] = av.w;
        }
        if (fullW) {
#pragma unroll
            for (int it = 0; it < 2; ++it) {
                int kk = kw + it * 16;
                const float4 wv = *(const float4*)(W + (size_t)(kb + kk) * ldw + n0 + nw);
                *(float4*)&Ws[kk][nw] = wv;
            }
        } else {
#pragma unroll
            for (int it = 0; it < 2; ++it) {
                int kk = kw + it * 16;
                const float* wrow = W + (size_t)(kb + kk) * ldw + n0 + nw;
                int gn = n0 + nw;
                float4 wv;
                wv.x = (gn + 0 < N) ? wrow[0] : 0.f;
                wv.y = (gn + 1 < N) ? wrow[1] : 0.f;
                wv.z = (gn + 2 < N) ? wrow[2] : 0.f;
                wv.w = (gn + 3 < N) ? wrow[3] : 0.f;
                *(float4*)&Ws[kk][nw] = wv;
            }
        }
        __syncthreads();
#pragma unroll
        for (int kk = 0; kk < 32; ++kk) {
            const float4 a = *(const float4*)&As[kk][ty * 4];
            const float4 w = *(const float4*)&Ws[kk][tx * 4];
            acc[0][0] += a.x * w.x; acc[0][1] += a.x * w.y; acc[0][2] += a.x * w.z; acc[0][3] += a.x * w.w;
            acc[1][0] += a.y * w.x; acc[1][1] += a.y * w.y; acc[1][2] += a.y * w.z; acc[1][3] += a.y * w.w;
            acc[2][0] += a.z * w.x; acc[2][1] += a.z * w.y; acc[2][2] += a.z * w.z; acc[2][3] += a.z * w.w;
            acc[3][0] += a.w * w.x; acc[3][1] += a.w * w.y; acc[3][2] += a.w * w.z; acc[3][3] += a.w * w.w;
        }
        __syncthreads();
    }
#pragma unroll
    for (int i = 0; i < 4; ++i) {
        int r = m0 + ty * 4 + i;
#pragma unroll
        for (int j = 0; j < 4; ++j) {
            int c = n0 + tx * 4 + j;
            if (c < N) {
                float v = acc[i][j];
                v += bias[c];
                if (RES) v += res[(size_t)r * ldres + c];
                if (RELU) v = v > 0.f ? v : 0.f;
                C[(size_t)r * ldc + c] = v;
            }
        }
    }
}

// =============================================================
// Attention scores (chunked over bh): local bh = blockIdx.z,
// global bh = bh0 + blockIdx.z. scores indexed by LOCAL bh.
// =============================================================
__global__ __launch_bounds__(256)
void attn_scores_kernel(const float* __restrict__ q, const float* __restrict__ kmat,
                        const int* __restrict__ mask, float* __restrict__ scores,
                        int Sq, int Sk, int bh0) {
    const int tid = threadIdx.x;
    const int tx = tid & 15, ty = tid >> 4;
    const int bhl = blockIdx.z;
    const int bhg = bh0 + bhl, b = bhg >> 3, h = bhg & 7;
    const int i0 = blockIdx.y * 64, j0 = blockIdx.x * 64;
    __shared__ float Qs[64][68];
    __shared__ float Ks[64][68];

    const int c4 = (tid & 15) * 4;
    const int r0 = tid >> 4;
#pragma unroll
    for (int it = 0; it < 4; ++it) {
        int i = r0 + it * 16;
        float4 qv = *(const float4*)(q + (size_t)(b * Sq + i0 + i) * 512 + h * 64 + c4);
        Qs[c4 + 0][i] = qv.x; Qs[c4 + 1][i] = qv.y; Qs[c4 + 2][i] = qv.z; Qs[c4 + 3][i] = qv.w;
        float4 kv = *(const float4*)(kmat + (size_t)(b * Sk + j0 + i) * 512 + h * 64 + c4);
        Ks[c4 + 0][i] = kv.x; Ks[c4 + 1][i] = kv.y; Ks[c4 + 2][i] = kv.z; Ks[c4 + 3][i] = kv.w;
    }
    __syncthreads();
    float acc[4][4];
#pragma unroll
    for (int i = 0; i < 4; ++i)
#pragma unroll
        for (int j = 0; j < 4; ++j) acc[i][j] = 0.f;
#pragma unroll
    for (int kk = 0; kk < 64; ++kk) {
        const float4 a = *(const float4*)&Qs[kk][ty * 4];
        const float4 w = *(const float4*)&Ks[kk][tx * 4];
        acc[0][0] += a.x * w.x; acc[0][1] += a.x * w.y; acc[0][2] += a.x * w.z; acc[0][3] += a.x * w.w;
        acc[1][0] += a.y * w.x; acc[1][1] += a.y * w.y; acc[1][2] += a.y * w.z; acc[1][3] += a.y * w.w;
        acc[2][0] += a.z * w.x; acc[2][1] += a.z * w.y; acc[2][2] += a.z * w.z; acc[2][3] += a.z * w.w;
        acc[3][0] += a.w * w.x; acc[3][1] += a.w * w.y; acc[3][2] += a.w * w.z; acc[3][3] += a.w * w.w;
    }
#pragma unroll
    for (int i = 0; i < 4; ++i) {
        int gi = i0 + ty * 4 + i;
#pragma unroll
        for (int j = 0; j < 4; ++j) {
            int gj = j0 + tx * 4 + j;
            float s = acc[i][j] * 0.125f;
            if (mask[b * Sk + gj] == 0) s = -1e9f;
            scores[((size_t)bhl * Sq + gi) * Sk + gj] = s;
        }
    }
}

// =============================================================
// Softmax over rows of length Sk==512 (one block per row), in place
// =============================================================
__global__ __launch_bounds__(256)
void softmax_kernel(float* __restrict__ p, int Sk) {
    __shared__ float red[256];
    const int row = blockIdx.x, tid = threadIdx.x;
    float* pr = p + (size_t)row * Sk;
    float v0 = pr[tid], v1 = pr[tid + 256];
    red[tid] = fmaxf(v0, v1);
    __syncthreads();
    for (int st = 128; st > 0; st >>= 1) { if (tid < st) red[tid] = fmaxf(red[tid], red[tid + st]); __syncthreads(); }
    float mx = red[0];
    __syncthreads();
    float e0 = __expf(v0 - mx), e1 = __expf(v1 - mx);
    red[tid] = e0 + e1;
    __syncthreads();
    for (int st = 128; st > 0; st >>= 1) { if (tid < st) red[tid] += red[tid + st]; __syncthreads(); }
    float inv = 1.f / red[0];
    pr[tid] = e0 * inv;
    pr[tid + 256] = e1 * inv;
}

// =============================================================
// P@V (chunked): local bh = blockIdx.y, global bh = bh0+blockIdx.y
// out[b, i, h*64+n] = sum_j p[bhl,i,j] * v[b,j,h*64+n]
// =============================================================
__global__ __launch_bounds__(256)
void attn_pv_kernel(const float* __restrict__ scores, const float* __restrict__ v,
                    float* __restrict__ out, int Sq, int Sk, int bh0) {
    const int tid = threadIdx.x;
    const int tx = tid & 15, ty = tid >> 4;
    const int bhl = blockIdx.y;
    const int bhg = bh0 + bhl, b = bhg >> 3, h = bhg & 7;
    const int i0 = blockIdx.x * 64;
    __shared__ float As[32][68];
    __shared__ float Vs[32][68];
    const int kqa = (tid & 7) * 4, ma = tid >> 3;
    const int nw = (tid & 15) * 4, kw = tid >> 4;
    float acc[4][4];
#pragma unroll
    for (int i = 0; i < 4; ++i)
#pragma unroll
        for (int j = 0; j < 4; ++j) acc[i][j] = 0.f;
    const float* srow = scores + (size_t)bhl * Sq * Sk;
    for (int kb = 0; kb < Sk; kb += 32) {
#pragma unroll
        for (int it = 0; it < 2; ++it) {
            int mm = ma + it * 32;
            const float4 av = *(const float4*)(srow + (size_t)(i0 + mm) * Sk + kb + kqa);
            As[kqa + 0][mm] = av.x;
            As[kqa + 1][mm] = av.y;
            As[kqa + 2][mm] = av.z;
            As[kqa + 3][mm] = av.w;
        }
#pragma unroll
        for (int it = 0; it < 2; ++it) {
            int kk2 = kw + it * 16;
            const float4 vv = *(const float4*)(v + (size_t)(b * Sk + kb + kk2) * 512 + h * 64 + nw);
            *(float4*)&Vs[kk2][nw] = vv;
        }
        __syncthreads();
#pragma unroll
        for (int kk = 0; kk < 32; ++kk) {
            const float4 a = *(const float4*)&As[kk][ty * 4];
            const float4 w = *(const float4*)&Vs[kk][tx * 4];
            acc[0][0] += a.x * w.x; acc[0][1] += a.x * w.y; acc[0][2] += a.x * w.z; acc[0][3] += a.x * w.w;
            acc[1][0] += a.y * w.x; acc[1][1] += a.y * w.y; acc[1][2] += a.y * w.z; acc[1][3] += a.y * w.w;
            acc[2][0] += a.z * w.x; acc[2][1] += a.z * w.y; acc[2][2] += a.z * w.z; acc[2][3] += a.z * w.w;
            acc[3][0] += a.w * w.x; acc[3][1] += a.w * w.y; acc[3][2] += a.w * w.z; acc[3][3] += a.w * w.w;
        }
        __syncthreads();
    }
#pragma unroll
    for (int i = 0; i < 4; ++i)
#pragma unroll
        for (int j = 0; j < 4; ++j)
            out[(size_t)(b * Sq + i0 + ty * 4 + i) * 512 + h * 64 + tx * 4 + j] = acc[i][j];
}

// =============================================================
// In-place log_softmax on f32 rows of length N (one block/row)
// =============================================================
__global__ __launch_bounds__(256)
void logsoftmax_kernel(float* __restrict__ out, int N) {
    __shared__ float red[256];
    const int row = blockIdx.x, tid = threadIdx.x;
    float* pr = out + (size_t)row * N;
    float mx = -3.4e38f;
    for (int c = tid; c < N; c += 256) mx = fmaxf(mx, pr[c]);
    red[tid] = mx;
    __syncthreads();
    for (int st = 128; st > 0; st >>= 1) { if (tid < st) red[tid] = fmaxf(red[tid], red[tid + st]); __syncthreads(); }
    mx = red[0];
    __syncthreads();
    float s = 0.f;
    for (int c = tid; c < N; c += 256) s += __expf(pr[c] - mx);
    red[tid] = s;
    __syncthreads();
    for (int st = 128; st > 0; st >>= 1) { if (tid < st) red[tid] += red[tid + st]; __syncthreads(); }
    float ls = mx + __logf(red[0]);
    for (int c = tid; c < N; c += 256) pr[c] = pr[c] - ls;
}

// =============================================================
// Host orchestration — ws usage EXACTLY 64 MB (16,777,216 floats)
// =============================================================
extern "C" void kernel_launch(void* const* d_in, const int* in_sizes, int n_in,
                              void* d_out, int out_size, void* d_ws, size_t ws_size,
                              hipStream_t stream) {
    const int*   src       = (const int*)d_in[0];
    const int*   tgt       = (const int*)d_in[1];
    const int*   src_mask  = (const int*)d_in[2];
    // d_in[3] = tgt_mask (unused by reference)
    const float* emb_src   = (const float*)d_in[4];
    const float* emb_tgt   = (const float*)d_in[5];
    const float* pe        = (const float*)d_in[6];
    const float* enc_qkvo_w = (const float*)d_in[7];
    const float* enc_qkvo_b = (const float*)d_in[8];
    const float* enc_ff_w1  = (const float*)d_in[9];
    const float* enc_ff_b1  = (const float*)d_in[10];
    const float* enc_ff_w2  = (const float*)d_in[11];
    const float* enc_ff_b2  = (const float*)d_in[12];
    const float* enc_ln_g   = (const float*)d_in[13];
    const float* enc_ln_b   = (const float*)d_in[14];
    const float* enc_norm_g = (const float*)d_in[15];
    const float* enc_norm_b = (const float*)d_in[16];
    const float* dec_qkvo_w = (const float*)d_in[17];
    const float* dec_qkvo_b = (const float*)d_in[18];
    const float* dec_ff_w1  = (const float*)d_in[19];
    const float* dec_ff_b1  = (const float*)d_in[20];
    const float* dec_ff_w2  = (const float*)d_in[21];
    const float* dec_ff_b2  = (const float*)d_in[22];
    const float* dec_ln_g   = (const float*)d_in[23];
    const float* dec_ln_b   = (const float*)d_in[24];
    const float* dec_norm_g = (const float*)d_in[25];
    const float* dec_norm_b = (const float*)d_in[26];
    const float* gen_w      = (const float*)d_in[27];
    const float* gen_b      = (const float*)d_in[28];

    float* ws  = (float*)d_ws;
    float* x   = ws;               // 2,097,152 (also decoder y)
    float* h   = x + 2097152;
    float* k   = h + 2097152;
    float* v   = k + 2097152;
    float* q   = v + 2097152;      // also ao (chunk-disjoint reuse)
    float* mem = q + 2097152;
    float* sf  = mem + 2097152;    // 4,194,304: scores-chunk / ffn-mid-chunk
    float* ao  = q;

    // ---------------- encoder ----------------
    const int totE = 8 * 512 * 512;
    embed_kernel<<<totE / 256, 256, 0, stream>>>(src, emb_src, pe, x, 512, totE);

    for (int l = 0; l < 8; ++l) {
        const float* w    = enc_qkvo_w + (size_t)l * 4 * 262144;
        const float* bqkv = enc_qkvo_b + (size_t)l * 2048;
        layernorm_kernel<<<4096, 256, 0, stream>>>(x, enc_ln_g + (l * 2) * 512, enc_ln_b + (l * 2) * 512, h);
        gemm_kernel<0,0><<<dim3(8, 64), 256, 0, stream>>>(h, 512, w + 0 * 262144, 512, bqkv + 0,    nullptr, 0, q, 512, 4096, 512, 512);
        gemm_kernel<0,0><<<dim3(8, 64), 256, 0, stream>>>(h, 512, w + 1 * 262144, 512, bqkv + 512,  nullptr, 0, k, 512, 4096, 512, 512);
        gemm_kernel<0,0><<<dim3(8, 64), 256, 0, stream>>>(h, 512, w + 2 * 262144, 512, bqkv + 1024, nullptr, 0, v, 512, 4096, 512, 512);
        for (int c = 0; c < 4; ++c) {   // 2 batches (16 bh) per chunk
            int bh0 = c * 16;
            attn_scores_kernel<<<dim3(8, 8, 16), 256, 0, stream>>>(q, k, src_mask, sf, 512, 512, bh0);
            softmax_kernel<<<16 * 512, 256, 0, stream>>>(sf, 512);
            attn_pv_kernel<<<dim3(8, 16), 256, 0, stream>>>(sf, v, ao, 512, 512, bh0);
        }
        gemm_kernel<0,1><<<dim3(8, 64), 256, 0, stream>>>(ao, 512, w + 3 * 262144, 512, bqkv + 1536, x, 512, x, 512, 4096, 512, 512);
        layernorm_kernel<<<4096, 256, 0, stream>>>(x, enc_ln_g + (l * 2 + 1) * 512, enc_ln_b + (l * 2 + 1) * 512, h);
        for (int r = 0; r < 2; ++r) {   // 2048-row chunks
            int r0 = r * 2048;
            gemm_kernel<1,0><<<dim3(32, 32), 256, 0, stream>>>(h + (size_t)r0 * 512, 512, enc_ff_w1 + (size_t)l * 1048576, 2048, enc_ff_b1 + l * 2048, nullptr, 0, sf, 2048, 2048, 2048, 512);
            gemm_kernel<0,1><<<dim3(8, 32), 256, 0, stream>>>(sf, 2048, enc_ff_w2 + (size_t)l * 1048576, 512, enc_ff_b2 + l * 512, x + (size_t)r0 * 512, 512, x + (size_t)r0 * 512, 512, 2048, 512, 2048);
        }
    }
    layernorm_kernel<<<4096, 256, 0, stream>>>(x, enc_norm_g, enc_norm_b, mem);

    // ---------------- decoder (cross-attn + FFN only); y reuses x ----------------
    float* y = x;
    const int totD = 8 * 256 * 512;
    embed_kernel<<<totD / 256, 256, 0, stream>>>(tgt, emb_tgt, pe, y, 256, totD);

    for (int l = 0; l < 8; ++l) {
        const float* w    = dec_qkvo_w + (size_t)l * 4 * 262144;
        const float* bqkv = dec_qkvo_b + (size_t)l * 2048;
        layernorm_kernel<<<2048, 256, 0, stream>>>(y, dec_ln_g + (l * 2) * 512, dec_ln_b + (l * 2) * 512, h);
        gemm_kernel<0,0><<<dim3(8, 32), 256, 0, stream>>>(h,   512, w + 0 * 262144, 512, bqkv + 0,    nullptr, 0, q, 512, 2048, 512, 512);
        gemm_kernel<0,0><<<dim3(8, 64), 256, 0, stream>>>(mem, 512, w + 1 * 262144, 512, bqkv + 512,  nullptr, 0, k, 512, 4096, 512, 512);
        gemm_kernel<0,0><<<dim3(8, 64), 256, 0, stream>>>(mem, 512, w + 2 * 262144, 512, bqkv + 1024, nullptr, 0, v, 512, 4096, 512, 512);
        for (int c = 0; c < 4; ++c) {
            int bh0 = c * 16;
            attn_scores_kernel<<<dim3(8, 4, 16), 256, 0, stream>>>(q, k, src_mask, sf, 256, 512, bh0);
            softmax_kernel<<<16 * 256, 256, 0, stream>>>(sf, 512);
            attn_pv_kernel<<<dim3(4, 16), 256, 0, stream>>>(sf, v, ao, 256, 512, bh0);
        }
        gemm_kernel<0,1><<<dim3(8, 32), 256, 0, stream>>>(ao, 512, w + 3 * 262144, 512, bqkv + 1536, y, 512, y, 512, 2048, 512, 512);
        layernorm_kernel<<<2048, 256, 0, stream>>>(y, dec_ln_g + (l * 2 + 1) * 512, dec_ln_b + (l * 2 + 1) * 512, h);
        gemm_kernel<1,0><<<dim3(32, 32), 256, 0, stream>>>(h, 512, dec_ff_w1 + (size_t)l * 1048576, 2048, dec_ff_b1 + l * 2048, nullptr, 0, sf, 2048, 2048, 2048, 512);
        gemm_kernel<0,1><<<dim3(8, 32), 256, 0, stream>>>(sf, 2048, dec_ff_w2 + (size_t)l * 1048576, 512, dec_ff_b2 + l * 512, y, 512, y, 512, 2048, 512, 2048);
    }
    layernorm_kernel<<<2048, 256, 0, stream>>>(y, dec_norm_g, dec_norm_b, h);

    // ---------------- generator + log_softmax ----------------
    float* out = (float*)d_out;
    gemm_kernel<0,0><<<dim3(501, 32), 256, 0, stream>>>(h, 512, gen_w, 32001, gen_b, nullptr, 0, out, 32001, 2048, 32001, 512);
    logsoftmax_kernel<<<2048, 256, 0, stream>>>(out, 32001);
}